// Round 1
// baseline (23.475 us; speedup 1.0000x reference)
//
#include <hip/hip_runtime.h>
#include <math.h>

#define SS 7
#define CH 30
#define NCLS 20
#define PRED_STRIDE (CH * SS * SS)   // 1470
#define IMGF 448.0f

__device__ __forceinline__ float sigf(float x) {
    return 1.0f / (1.0f + __expf(-x));
}

__global__ __launch_bounds__(64) void yolo_loss_kernel(
    const float* __restrict__ pred,
    const float* __restrict__ annot,
    float* __restrict__ out, int n)
{
    int b = blockIdx.x * blockDim.x + threadIdx.x;
    float total = 0.0f;

    if (b < n) {
        // ---- load annotation (2 boxes x 5) ----
        const float* g = annot + (size_t)b * 10;
        float gx[2], gy[2], gw[2], gh[2], gc[2];
        #pragma unroll
        for (int k = 0; k < 2; ++k) {
            gx[k] = g[k * 5 + 0];
            gy[k] = g[k * 5 + 1];
            gw[k] = g[k * 5 + 2];
            gh[k] = g[k * 5 + 3];
            gc[k] = g[k * 5 + 4];
        }

        // ---- grid cell indices (replicate reference op order exactly) ----
        int ti[2], tj[2];
        #pragma unroll
        for (int k = 0; k < 2; ++k) {
            float nx = gx[k] / IMGF;
            float ny = gy[k] / IMGF;
            float nw = gw[k] / IMGF;
            float nh = gh[k] / IMGF;
            ti[k] = (int)floorf((nx + nw * 0.5f) * 7.0f);
            tj[k] = (int)floorf((ny + nh * 0.5f) * 7.0f);
        }

        // ---- gather the 30-channel cell at (ti[1], tj[1]) ----
        const float* base = pred + (size_t)b * PRED_STRIDE + ti[1] * SS + tj[1];
        float cell[CH];
        #pragma unroll
        for (int c = 0; c < CH; ++c) cell[c] = base[c * (SS * SS)];
        #pragma unroll
        for (int c = 0; c < CH; ++c) cell[c] = sigf(cell[c]);

        float b1x = cell[0], b1y = cell[1], b1w = cell[2], b1h = cell[3], b1c = cell[4];
        float b2x = cell[5], b2y = cell[6], b2w = cell[7], b2h = cell[8], b2c = cell[9];

        // ---- per-annotation loss ----
        #pragma unroll
        for (int k = 0; k < 2; ++k) {
            // IoU of box1 vs gt (note: boxes are sigmoid-space, gt is raw — as in reference)
            float x1, y1, x2, y2, inter, uni, iou1, iou2;

            x1 = fmaxf(b1x, gx[k]);
            y1 = fmaxf(b1y, gy[k]);
            x2 = fminf(b1x + b1w, gx[k] + gw[k]);
            y2 = fminf(b1y + b1h, gy[k] + gh[k]);
            inter = fmaxf(x2 - x1, 0.0f) * fmaxf(y2 - y1, 0.0f);
            uni = b1w * b1h + gw[k] * gh[k] - inter;
            iou1 = inter / (uni + 1e-6f);

            x1 = fmaxf(b2x, gx[k]);
            y1 = fmaxf(b2y, gy[k]);
            x2 = fminf(b2x + b2w, gx[k] + gw[k]);
            y2 = fminf(b2y + b2h, gy[k] + gh[k]);
            inter = fmaxf(x2 - x1, 0.0f) * fmaxf(y2 - y1, 0.0f);
            uni = b2w * b2h + gw[k] * gh[k] - inter;
            iou2 = inter / (uni + 1e-6f);

            bool pick1 = iou1 > iou2;
            float sx = pick1 ? b1x : b2x;
            float sy = pick1 ? b1y : b2y;
            float sw = pick1 ? b1w : b2w;
            float sh = pick1 ? b1h : b2h;
            float sc = pick1 ? b1c : b2c;

            float ngx = gx[k] / IMGF;
            float ngy = gy[k] / IMGF;
            float ngw = gw[k] / IMGF;
            float ngh = gh[k] / IMGF;

            float dx = ngx - sx, dy = ngy - sy;
            float xy = 5.0f * (dx * dx + dy * dy);
            float dw = sqrtf(ngw) - sqrtf(sw);
            float dh = sqrtf(ngh) - sqrtf(sh);
            float wh = 5.0f * (dw * dw + dh * dh);
            float ob = (1.0f - sc) * (1.0f - sc);

            int ci = (int)gc[k];
            float cls = 0.0f;
            #pragma unroll
            for (int c = 0; c < NCLS; ++c) {
                float oh = (c == ci) ? 1.0f : 0.0f;
                float d = oh - cell[10 + c];
                cls += d * d;
            }

            total += xy + wh + ob + cls;
        }

        // ---- last "no-object" cell: largest idx with any_k((i!=ti[k]) && (j!=tj[k])) ----
        int last = 48;
        #pragma unroll 1
        for (int idx = 48; idx >= 0; --idx) {
            int i = idx / SS, j = idx % SS;
            bool m = ((i != ti[0]) && (j != tj[0])) || ((i != ti[1]) && (j != tj[1]));
            if (m) { last = idx; break; }
        }
        float conf = sigf(pred[(size_t)b * PRED_STRIDE + 9 * (SS * SS) + (last / SS) * SS + (last % SS)]);
        total += 2.0f * conf * conf;   // nobj term broadcast over the 2 annot boxes
    }

    // ---- wave reduction (wave64) + one atomic per wave ----
    #pragma unroll
    for (int off = 32; off > 0; off >>= 1)
        total += __shfl_down(total, off, 64);
    if ((threadIdx.x & 63) == 0)
        atomicAdd(out, total);
}

extern "C" void kernel_launch(void* const* d_in, const int* in_sizes, int n_in,
                              void* d_out, int out_size, void* d_ws, size_t ws_size,
                              hipStream_t stream) {
    const float* pred  = (const float*)d_in[0];
    const float* annot = (const float*)d_in[1];
    float* out = (float*)d_out;
    int n = in_sizes[0] / PRED_STRIDE;   // 16384

    hipMemsetAsync(out, 0, sizeof(float) * out_size, stream);
    int threads = 64;
    int blocks = (n + threads - 1) / threads;
    yolo_loss_kernel<<<blocks, threads, 0, stream>>>(pred, annot, out, n);
}